// Round 7
// baseline (319.065 us; speedup 1.0000x reference)
//
#include <hip/hip_runtime.h>
#include <hip/hip_bf16.h>

typedef __attribute__((ext_vector_type(8))) short bf16x8;
typedef __attribute__((ext_vector_type(4))) float f32x4;

__device__ inline unsigned short f2bf(float x) {
  unsigned int u = __float_as_uint(x);
  unsigned int r = (u + 0x7fffu + ((u >> 16) & 1u)) >> 16;
  return (unsigned short)r;
}

// ---------------- prep weights (blocks 0..127) + zero cnt (blocks >=128) ------
__global__ __launch_bounds__(256) void prep_zero(
    const float* __restrict__ Wm, const float* __restrict__ w0,
    const float* __restrict__ w1, const float* __restrict__ w2,
    const float* __restrict__ Wn,
    unsigned short* __restrict__ CmbT, unsigned short* __restrict__ W0T,
    unsigned short* __restrict__ W1T, unsigned short* __restrict__ W2nT,
    int* __restrict__ cnt, int N)
{
  int b = blockIdx.x;
  if (b < 128) {
    int n = b;
    int k = threadIdx.x;
    CmbT[n*256 + k] = f2bf(Wm[k*128 + n]);
    W0T [n*256 + k] = f2bf(w0[k*128 + n]);
    W2nT[n*256 + k] = f2bf((k < 128) ? w2[k*128 + n] : Wn[(k-128)*128 + n]);
    if (k < 128) W1T[n*128 + k] = f2bf(w1[k*128 + n]);
  } else {
    int base = (b - 128) * 2048 + threadIdx.x;
    #pragma unroll
    for (int it = 0; it < 8; ++it) {
      int i = base + it * 256;
      if (i < N) cnt[i] = 0;
    }
  }
}

// ---------------- counting sort of edges by receiver ----------------
__global__ __launch_bounds__(256) void hist_recv(
    const int* __restrict__ recv, int* __restrict__ cnt, int E)
{
  int e = blockIdx.x * 256 + threadIdx.x;
  if (e < E) atomicAdd(&cnt[recv[e]], 1);
}

__global__ __launch_bounds__(1024) void scan_counts(
    const int* __restrict__ cnt, int* __restrict__ offs,
    int* __restrict__ cursor, int N)
{
  __shared__ int part[1024];
  const int t = threadIdx.x;
  const int C = (N + 1023) / 1024;
  const int lo = t * C;
  const int hi = min(lo + C, N);
  int s = 0;
  for (int i = lo; i < hi; ++i) s += cnt[i];
  part[t] = s;
  __syncthreads();
  for (int off = 1; off < 1024; off <<= 1) {
    int v = (t >= off) ? part[t - off] : 0;
    __syncthreads();
    part[t] += v;
    __syncthreads();
  }
  int run = part[t] - s;
  for (int i = lo; i < hi; ++i) {
    offs[i] = run; cursor[i] = run;
    run += cnt[i];
  }
  if (t == 1023) offs[N] = part[1023];
}

// writes {edge id, sender id} as one 8B record in receiver-sorted order
__global__ __launch_bounds__(256) void scatter_ids(
    const int* __restrict__ recv, const int* __restrict__ send,
    int* __restrict__ cursor, int2* __restrict__ pairs, int E)
{
  int e = blockIdx.x * 256 + threadIdx.x;
  if (e >= E) return;
  int pos = atomicAdd(&cursor[recv[e]], 1);
  pairs[pos] = make_int2(e, send[e]);
}

// ---------------- fused: gather-aggregate + 4 MFMA GEMMs + LayerNorm ---------
__device__ inline bf16x8 ldsFragA(const unsigned short* tile, int rowBytes,
                                  int row, int kk, int lg) {
  int byteOff = row * rowBytes + ((((kk << 6) + (lg << 4))) ^ ((row & 7) << 4));
  return *reinterpret_cast<const bf16x8*>(
      reinterpret_cast<const char*>(tile) + byteOff);
}
__device__ inline bf16x8 glbFragB(const unsigned short* WT, int kElems,
                                  int n, int lr, int kk, int lg) {
  size_t el = (size_t)(n*16 + lr) * kElems + kk*32 + lg*8;
  return *reinterpret_cast<const bf16x8*>(WT + el);
}

__global__ __launch_bounds__(256, 3) void fused_node(
    const float* __restrict__ nodes, const float* __restrict__ edges,
    const int* __restrict__ offs, const int2* __restrict__ pairs,
    const unsigned short* __restrict__ CmbT, const unsigned short* __restrict__ W0T,
    const unsigned short* __restrict__ W1T, const unsigned short* __restrict__ W2nT,
    const float* __restrict__ b0, const float* __restrict__ b1,
    const float* __restrict__ b2, const float* __restrict__ gam,
    const float* __restrict__ bet, float* __restrict__ out, int N)
{
  __shared__ unsigned short sS[64*256];   // 32KB gathered S tile; bufA/bufB alias
  __shared__ unsigned short sN[64*128];   // 16KB nodes tile
  __shared__ int sOffs[4][17];
  __shared__ float pS[4][64];
  __shared__ float pQ[4][64];

  unsigned short* bufA = sS;              // agg after G1; h1 after G3
  unsigned short* bufB = sS + 64*128;     // h0 after G2

  const int tid  = threadIdx.x;
  const int lane = tid & 63;
  const int w    = tid >> 6;           // wave: 16-node gather bucket; 32 GEMM cols
  const int lr = lane & 15;
  const int lg = lane >> 4;
  const int m0 = blockIdx.x * 64;

  // ---- stage nodes tile first (loads fly while gather starts) ----
  #pragma unroll
  for (int it = 0; it < 4; ++it) {
    int c = tid + (it << 8);
    int r = c >> 4, cc = c & 15;
    int gr = m0 + r; if (gr > N-1) gr = N-1;
    const float4* src = reinterpret_cast<const float4*>(nodes + (size_t)gr*128 + cc*8);
    float4 v0 = src[0], v1 = src[1];
    bf16x8 o;
    o[0]=(short)f2bf(v0.x); o[1]=(short)f2bf(v0.y); o[2]=(short)f2bf(v0.z); o[3]=(short)f2bf(v0.w);
    o[4]=(short)f2bf(v1.x); o[5]=(short)f2bf(v1.y); o[6]=(short)f2bf(v1.z); o[7]=(short)f2bf(v1.w);
    int dst = r*256 + ((cc << 4) ^ ((r & 7) << 4));
    *reinterpret_cast<bf16x8*>(reinterpret_cast<char*>(sN) + dst) = o;
  }

  // ---- gather phase: wave w aggregates nodes [m0+w*16, m0+w*16+16) ----
  {
    const int base = m0 + (w << 4);
    if (lane < 17) {
      int nidx = base + lane; if (nidx > N) nidx = N;
      sOffs[w][lane] = offs[nidx];
    }
    const int jstart = sOffs[w][0];
    const int jend   = sOffs[w][16];
    const int cs = (lane & 31) * 4;          // f32 column offset within row
    const bool isNode = lane < 32;
    const float* gbase = isNode ? nodes : edges;
    char* sSb = reinterpret_cast<char*>(sS);

    float4 acc = {0.f, 0.f, 0.f, 0.f};
    int nd = 0;
    int bound = sOffs[w][1];

    auto flush = [&]() {
      int row = (w << 4) + nd;
      ushort4 o;
      o.x = f2bf(acc.x); o.y = f2bf(acc.y); o.z = f2bf(acc.z); o.w = f2bf(acc.w);
      *reinterpret_cast<ushort4*>(sSb + row*512 + ((lane*8) ^ ((row & 7) << 4))) = o;
      acc.x = 0.f; acc.y = 0.f; acc.z = 0.f; acc.w = 0.f;
    };

    int j = jstart;
    if (j < jend) {
      const int jmax = jend - 1;
      int2 pb[8];
      #pragma unroll
      for (int k = 0; k < 8; ++k) pb[k] = pairs[min(j + k, jmax)];
      while (j < jend) {
        float4 v[8];
        #pragma unroll
        for (int k = 0; k < 8; ++k) {
          int rrow = isNode ? pb[k].y : pb[k].x;
          v[k] = *reinterpret_cast<const float4*>(gbase + (size_t)rrow*128 + cs);
        }
        int jn = j + 8;
        int2 pb2[8];
        if (jn < jend) {
          #pragma unroll
          for (int k = 0; k < 8; ++k) pb2[k] = pairs[min(jn + k, jmax)];
        }
        #pragma unroll
        for (int k = 0; k < 8; ++k) {
          int jj = j + k;
          if (jj < jend) {
            while (jj >= bound) {           // wave-uniform boundary crossing
              flush(); ++nd;
              bound = sOffs[w][nd + 1];
            }
            acc.x += v[k].x; acc.y += v[k].y; acc.z += v[k].z; acc.w += v[k].w;
          }
        }
        #pragma unroll
        for (int k = 0; k < 8; ++k) pb[k] = pb2[k];
        j = jn;
      }
    }
    while (nd < 16) { flush(); ++nd; }     // drain: current node + empty tail
  }

  f32x4 acc[4][2];
  bf16x8 b[2][4];

  // G1 first-half B loads (global) issue before the barrier
  #pragma unroll
  for (int nn = 0; nn < 2; ++nn)
    #pragma unroll
    for (int kk = 0; kk < 4; ++kk)
      b[nn][kk] = glbFragB(CmbT, 256, w*2 + nn, lr, kk, lg);

  __syncthreads();   // S1: sS(gathered) + sN staged

  // ======== GEMM1: agg = S(64x256) @ Wm ========
  #pragma unroll
  for (int rb = 0; rb < 4; ++rb)
    #pragma unroll
    for (int nn = 0; nn < 2; ++nn) { acc[rb][nn][0]=0.f; acc[rb][nn][1]=0.f; acc[rb][nn][2]=0.f; acc[rb][nn][3]=0.f; }
  #pragma unroll
  for (int rb = 0; rb < 4; ++rb)
    #pragma unroll
    for (int kk = 0; kk < 4; ++kk) {
      bf16x8 a = ldsFragA(sS, 512, rb*16 + lr, kk, lg);
      #pragma unroll
      for (int nn = 0; nn < 2; ++nn)
        acc[rb][nn] = __builtin_amdgcn_mfma_f32_16x16x32_bf16(a, b[nn][kk], acc[rb][nn], 0, 0, 0);
    }
  #pragma unroll
  for (int nn = 0; nn < 2; ++nn)
    #pragma unroll
    for (int kk = 0; kk < 4; ++kk)
      b[nn][kk] = glbFragB(CmbT, 256, w*2 + nn, lr, kk + 4, lg);
  #pragma unroll
  for (int rb = 0; rb < 4; ++rb)
    #pragma unroll
    for (int kk = 0; kk < 4; ++kk) {
      bf16x8 a = ldsFragA(sS, 512, rb*16 + lr, kk + 4, lg);
      #pragma unroll
      for (int nn = 0; nn < 2; ++nn)
        acc[rb][nn] = __builtin_amdgcn_mfma_f32_16x16x32_bf16(a, b[nn][kk], acc[rb][nn], 0, 0, 0);
    }
  __syncthreads();   // S2: all sS reads done before bufA overwrite

  // epilogue G1 -> bufA (agg)
  #pragma unroll
  for (int rb = 0; rb < 4; ++rb)
    #pragma unroll
    for (int nn = 0; nn < 2; ++nn) {
      int col = w*32 + nn*16 + lr;
      #pragma unroll
      for (int i = 0; i < 4; ++i) {
        int r = rb*16 + lg*4 + i;
        *reinterpret_cast<unsigned short*>(
            reinterpret_cast<char*>(bufA) + r*256 + ((col << 1) ^ ((r & 7) << 4))) = f2bf(acc[rb][nn][i]);
      }
    }
  // G2 first-half B loads before the barrier
  #pragma unroll
  for (int nn = 0; nn < 2; ++nn)
    #pragma unroll
    for (int kk = 0; kk < 4; ++kk)
      b[nn][kk] = glbFragB(W0T, 256, w*2 + nn, lr, kk, lg);
  __syncthreads();   // S3: bufA(agg) ready

  // ======== GEMM2: h0 = relu([nodes, agg] @ w0 + b0) -> bufB ========
  #pragma unroll
  for (int rb = 0; rb < 4; ++rb)
    #pragma unroll
    for (int nn = 0; nn < 2; ++nn) { acc[rb][nn][0]=0.f; acc[rb][nn][1]=0.f; acc[rb][nn][2]=0.f; acc[rb][nn][3]=0.f; }
  #pragma unroll
  for (int rb = 0; rb < 4; ++rb)
    #pragma unroll
    for (int kk = 0; kk < 4; ++kk) {
      bf16x8 a = ldsFragA(sN, 256, rb*16 + lr, kk, lg);
      #pragma unroll
      for (int nn = 0; nn < 2; ++nn)
        acc[rb][nn] = __builtin_amdgcn_mfma_f32_16x16x32_bf16(a, b[nn][kk], acc[rb][nn], 0, 0, 0);
    }
  #pragma unroll
  for (int nn = 0; nn < 2; ++nn)
    #pragma unroll
    for (int kk = 0; kk < 4; ++kk)
      b[nn][kk] = glbFragB(W0T, 256, w*2 + nn, lr, kk + 4, lg);
  #pragma unroll
  for (int rb = 0; rb < 4; ++rb)
    #pragma unroll
    for (int kk = 0; kk < 4; ++kk) {
      bf16x8 a = ldsFragA(bufA, 256, rb*16 + lr, kk, lg);
      #pragma unroll
      for (int nn = 0; nn < 2; ++nn)
        acc[rb][nn] = __builtin_amdgcn_mfma_f32_16x16x32_bf16(a, b[nn][kk], acc[rb][nn], 0, 0, 0);
    }
  // epilogue G2 -> bufB (disjoint from G2 readers; no barrier)
  #pragma unroll
  for (int nn = 0; nn < 2; ++nn) {
    int col = w*32 + nn*16 + lr;
    float bb = b0[col];
    #pragma unroll
    for (int rb = 0; rb < 4; ++rb)
      #pragma unroll
      for (int i = 0; i < 4; ++i) {
        int r = rb*16 + lg*4 + i;
        float x = fmaxf(acc[rb][nn][i] + bb, 0.f);
        *reinterpret_cast<unsigned short*>(
            reinterpret_cast<char*>(bufB) + r*256 + ((col << 1) ^ ((r & 7) << 4))) = f2bf(x);
      }
  }
  // G3 B loads (K=128)
  #pragma unroll
  for (int nn = 0; nn < 2; ++nn)
    #pragma unroll
    for (int kk = 0; kk < 4; ++kk)
      b[nn][kk] = glbFragB(W1T, 128, w*2 + nn, lr, kk, lg);
  __syncthreads();   // S4: bufB(h0) ready; all bufA reads done

  // ======== GEMM3: h1 = relu(h0 @ w1 + b1) -> bufA ========
  #pragma unroll
  for (int rb = 0; rb < 4; ++rb)
    #pragma unroll
    for (int nn = 0; nn < 2; ++nn) { acc[rb][nn][0]=0.f; acc[rb][nn][1]=0.f; acc[rb][nn][2]=0.f; acc[rb][nn][3]=0.f; }
  #pragma unroll
  for (int rb = 0; rb < 4; ++rb)
    #pragma unroll
    for (int kk = 0; kk < 4; ++kk) {
      bf16x8 a = ldsFragA(bufB, 256, rb*16 + lr, kk, lg);
      #pragma unroll
      for (int nn = 0; nn < 2; ++nn)
        acc[rb][nn] = __builtin_amdgcn_mfma_f32_16x16x32_bf16(a, b[nn][kk], acc[rb][nn], 0, 0, 0);
    }
  // epilogue G3 -> bufA (nobody reads bufA now)
  #pragma unroll
  for (int nn = 0; nn < 2; ++nn) {
    int col = w*32 + nn*16 + lr;
    float bb = b1[col];
    #pragma unroll
    for (int rb = 0; rb < 4; ++rb)
      #pragma unroll
      for (int i = 0; i < 4; ++i) {
        int r = rb*16 + lg*4 + i;
        float x = fmaxf(acc[rb][nn][i] + bb, 0.f);
        *reinterpret_cast<unsigned short*>(
            reinterpret_cast<char*>(bufA) + r*256 + ((col << 1) ^ ((r & 7) << 4))) = f2bf(x);
      }
  }
  // G4 first-half B loads
  #pragma unroll
  for (int nn = 0; nn < 2; ++nn)
    #pragma unroll
    for (int kk = 0; kk < 4; ++kk)
      b[nn][kk] = glbFragB(W2nT, 256, w*2 + nn, lr, kk, lg);
  __syncthreads();   // S5: bufA(h1) ready; all bufB reads done

  // ======== GEMM4: o = [h1, nodes] @ [w2; Wnode] + b2, LayerNorm ========
  #pragma unroll
  for (int rb = 0; rb < 4; ++rb)
    #pragma unroll
    for (int nn = 0; nn < 2; ++nn) { acc[rb][nn][0]=0.f; acc[rb][nn][1]=0.f; acc[rb][nn][2]=0.f; acc[rb][nn][3]=0.f; }
  #pragma unroll
  for (int rb = 0; rb < 4; ++rb)
    #pragma unroll
    for (int kk = 0; kk < 4; ++kk) {
      bf16x8 a = ldsFragA(bufA, 256, rb*16 + lr, kk, lg);
      #pragma unroll
      for (int nn = 0; nn < 2; ++nn)
        acc[rb][nn] = __builtin_amdgcn_mfma_f32_16x16x32_bf16(a, b[nn][kk], acc[rb][nn], 0, 0, 0);
    }
  #pragma unroll
  for (int nn = 0; nn < 2; ++nn)
    #pragma unroll
    for (int kk = 0; kk < 4; ++kk)
      b[nn][kk] = glbFragB(W2nT, 256, w*2 + nn, lr, kk + 4, lg);
  #pragma unroll
  for (int rb = 0; rb < 4; ++rb)
    #pragma unroll
    for (int kk = 0; kk < 4; ++kk) {
      bf16x8 a = ldsFragA(sN, 256, rb*16 + lr, kk, lg);
      #pragma unroll
      for (int nn = 0; nn < 2; ++nn)
        acc[rb][nn] = __builtin_amdgcn_mfma_f32_16x16x32_bf16(a, b[nn][kk], acc[rb][nn], 0, 0, 0);
    }
  // bias
  #pragma unroll
  for (int nn = 0; nn < 2; ++nn) {
    float bb = b2[w*32 + nn*16 + lr];
    #pragma unroll
    for (int rb = 0; rb < 4; ++rb)
      #pragma unroll
      for (int i = 0; i < 4; ++i) acc[rb][nn][i] += bb;
  }

  // ---- LayerNorm: cross-wave row reduction via LDS partials ----
  float rs[4][4], rq[4][4];
  #pragma unroll
  for (int rb = 0; rb < 4; ++rb)
    #pragma unroll
    for (int i = 0; i < 4; ++i) {
      float a0 = acc[rb][0][i], a1 = acc[rb][1][i];
      rs[rb][i] = a0 + a1;
      rq[rb][i] = a0*a0 + a1*a1;
    }
  #pragma unroll
  for (int msk = 1; msk < 16; msk <<= 1)
    #pragma unroll
    for (int rb = 0; rb < 4; ++rb)
      #pragma unroll
      for (int i = 0; i < 4; ++i) {
        rs[rb][i] += __shfl_xor(rs[rb][i], msk);
        rq[rb][i] += __shfl_xor(rq[rb][i], msk);
      }
  if (lr == 0) {
    #pragma unroll
    for (int rb = 0; rb < 4; ++rb)
      #pragma unroll
      for (int i = 0; i < 4; ++i) {
        int r = rb*16 + lg*4 + i;
        pS[w][r] = rs[rb][i];
        pQ[w][r] = rq[rb][i];
      }
  }
  __syncthreads();

  float gmul[2], gadd[2];
  #pragma unroll
  for (int nn = 0; nn < 2; ++nn) {
    int col = w*32 + nn*16 + lr;
    gmul[nn] = gam[col]; gadd[nn] = bet[col];
  }
  #pragma unroll
  for (int rb = 0; rb < 4; ++rb)
    #pragma unroll
    for (int i = 0; i < 4; ++i) {
      int r = rb*16 + lg*4 + i;
      float sum = pS[0][r] + pS[1][r] + pS[2][r] + pS[3][r];
      float sq  = pQ[0][r] + pQ[1][r] + pQ[2][r] + pQ[3][r];
      float mean = sum * (1.f/128.f);
      float var  = fmaxf(sq * (1.f/128.f) - mean*mean, 0.f);
      float rstd = rsqrtf(var + 1e-6f);
      int grow = m0 + r;
      if (grow < N) {
        #pragma unroll
        for (int nn = 0; nn < 2; ++nn) {
          int col = w*32 + nn*16 + lr;
          out[(size_t)grow*128 + col] = (acc[rb][nn][i] - mean) * rstd * gmul[nn] + gadd[nn];
        }
      }
    }
}

extern "C" void kernel_launch(void* const* d_in, const int* in_sizes, int n_in,
                              void* d_out, int out_size, void* d_ws, size_t ws_size,
                              hipStream_t stream) {
  const float* nodes     = (const float*)d_in[0];
  const float* edges     = (const float*)d_in[1];
  const int*   senders   = (const int*)d_in[2];
  const int*   receivers = (const int*)d_in[3];
  const float* Wm  = (const float*)d_in[4];
  const float* Wn  = (const float*)d_in[5];
  const float* w0  = (const float*)d_in[6];
  const float* b0  = (const float*)d_in[7];
  const float* w1  = (const float*)d_in[8];
  const float* b1  = (const float*)d_in[9];
  const float* w2  = (const float*)d_in[10];
  const float* b2  = (const float*)d_in[11];
  const float* gam = (const float*)d_in[12];
  const float* bet = (const float*)d_in[13];
  const int N = in_sizes[0] / 128;
  const int E = in_sizes[1] / 128;

  char* ws = (char*)d_ws;
  int2* pairs = (int2*)ws;                                 // [E] {edge, sender}
  unsigned short* CmbT = (unsigned short*)(ws + (size_t)E * 8);  // [128][256]
  unsigned short* W0T  = CmbT + 128*256;                   // [128][256]
  unsigned short* W1T  = W0T + 128*256;                    // [128][128]
  unsigned short* W2nT = W1T + 128*128;                    // [128][256]
  int* cnt    = (int*)(W2nT + 128*256);                    // [N]
  int* offs   = cnt + N;                                   // [N+1]
  int* cursor = offs + N + 1;                              // [N]

  int zBlocks = (N + 2047) / 2048;
  prep_zero<<<128 + zBlocks, 256, 0, stream>>>(Wm, w0, w1, w2, Wn,
                                               CmbT, W0T, W1T, W2nT, cnt, N);

  int eBlocks = (E + 255) / 256;
  hist_recv<<<eBlocks, 256, 0, stream>>>(receivers, cnt, E);
  scan_counts<<<1, 1024, 0, stream>>>(cnt, offs, cursor, N);
  scatter_ids<<<eBlocks, 256, 0, stream>>>(receivers, senders, cursor, pairs, E);

  int nodeBlocks = (N + 63) / 64;
  fused_node<<<nodeBlocks, 256, 0, stream>>>(nodes, edges, offs, pairs,
                                             CmbT, W0T, W1T, W2nT,
                                             b0, b1, b2, gam, bet, (float*)d_out, N);
}